// Round 2
// baseline (179.510 us; speedup 1.0000x reference)
//
#include <hip/hip_runtime.h>
#include <hip/hip_bf16.h>
#include <hip/hip_fp8.h>

#define N_ROWS 8192
#define NZ 16384           // rows of Z = [An; Bn]
#define DIM 256
#define TAU_INV 2.0f
#define BT 128             // block tile (square)
#define NTILE 128          // NZ / BT
#define NTRI (NTILE * (NTILE + 1) / 2)   // 8256 upper-tri tiles
#define NCHUNK 16
#define SEGT 4             // tiles per strip segment
#define NSEG 2112          // sum over ti of ceil((128-ti)/4)

typedef float f32x4 __attribute__((ext_vector_type(4)));
typedef long lx2 __attribute__((ext_vector_type(2)));   // 16B = 2 fp8 MFMA operands

// ---------------------------------------------------------------------------
// Kernel 1: one WAVE per row. L2-normalize, scale by 16, quantize to OCP fp8
// e4m3, write Z8 K-INTERLEAVED: each 64B chunk stores its eight 8B K-groups
// as [g0 g4 g1 g5 g2 g6 g3 g7] so one 16B granule = operand pair (g, g+4)
// for two consecutive MFMA K-steps. Same permutation for A and B -> neutral.
// pos[i] = (1/256)*dot(quantized an, bn).
// ---------------------------------------------------------------------------
__global__ __launch_bounds__(256) void normalize_kernel(
    const float* __restrict__ z1, const float* __restrict__ z2,
    unsigned char* __restrict__ Z8, float* __restrict__ pos)
{
    const int tid = threadIdx.x;
    const int wave = tid >> 6;
    const int lane = tid & 63;
    const int row = blockIdx.x * 4 + wave;      // 0..8191

    const float4 a = ((const float4*)(z1 + (size_t)row * DIM))[lane];
    const float4 b = ((const float4*)(z2 + (size_t)row * DIM))[lane];

    auto wsum = [&](float v) -> float {
        #pragma unroll
        for (int m = 1; m < 64; m <<= 1) v += __shfl_xor(v, m, 64);
        return v;
    };

    const float na2 = wsum(a.x*a.x + a.y*a.y + a.z*a.z + a.w*a.w);
    const float nb2 = wsum(b.x*b.x + b.y*b.y + b.z*b.z + b.w*b.w);
    const float sa = 16.0f / sqrtf(na2);   // norms ~16; eps never binds
    const float sb = 16.0f / sqrtf(nb2);

    const float av[4] = {a.x*sa, a.y*sa, a.z*sa, a.w*sa};
    const float bv[4] = {b.x*sb, b.y*sb, b.z*sb, b.w*sb};
    unsigned char pa[4], pb[4];
    float qd = 0.0f;
    #pragma unroll
    for (int k = 0; k < 4; ++k) {
        __hip_fp8_e4m3 qa(av[k]);
        __hip_fp8_e4m3 qb(bv[k]);
        pa[k] = qa.__x; pb[k] = qb.__x;
        qd += float(qa) * float(qb);
    }
    // interleaved write: lane owns half (lane&1) of local K-group (lane>>1)&7
    const int g  = (lane >> 1) & 7;
    const int pp = ((g & 3) << 1) | (g >> 2);          // interleaved 8B slot
    const int off = (lane >> 4) * 64 + pp * 8 + (lane & 1) * 4;
    *(uchar4*)(Z8 + (size_t)row * DIM + off) = *(uchar4*)pa;
    *(uchar4*)(Z8 + (size_t)(N_ROWS + row) * DIM + off) = *(uchar4*)pb;

    qd = wsum(qd);
    if (lane == 0) pos[row] = qd * 0.00390625f;   // /256 -> quantized sim
}

// ---------------------------------------------------------------------------
// Kernel 2: symmetric fp8 gram, upper triangle, STRIP-SEGMENTED.
// Each block owns one ti-strip segment of up to SEGT=4 consecutive tj tiles:
//   - A panel (128 rows x 256B, both K-halves) staged ONCE per segment (32KB)
//   - B half-panels (16KB) stream through a 2-slot ring, prefetched one
//     half-iteration ahead: [sync] -> issue stage(h+1) -> compute(h).
//     Every stage gets a full 64-MFMA compute phase of cover before the
//     __syncthreads() (vmcnt(0)) that precedes its first reader. 2 barriers
//     per tile, no zero-cover drains (was: 3 barriers + 2 cold drains).
// Same R12 compute core (16B-granule XOR swizzle, conflict-free, b128 frag
// reads, interleaved staging). s_setprio(1) wraps the MFMA clusters (T5).
// Epilogue identical math; row partials stored as float4 so 4 lanes form one
// full 64B line per instruction (kills TCC partial-sector RMW: was +60MB
// FETCH / +65MB WRITE).
// ---------------------------------------------------------------------------
template <bool TWO_STAGE>
__global__ __launch_bounds__(256, 2) void gram_kernel(
    const unsigned char* __restrict__ Z,
    float* __restrict__ part, float* __restrict__ S)
{
    // XCD band remap over segments (2112 = 8 * 264), then segment decode.
    const int sid = (blockIdx.x & 7) * (NSEG / 8) + (blockIdx.x >> 3);
    // strips grouped by 4: group g covers ti = 4g..4g+3, each strip in the
    // group has v = 32-g segments; cum(4g) = 130g - 2g^2 segments before it.
    int g = (int)((130.0f - sqrtf(16900.0f - 8.0f * (float)sid)) * 0.25f);
    g = g < 0 ? 0 : (g > 31 ? 31 : g);
    while (130 * g - 2 * g * g > sid) --g;
    while (g < 31 && 130 * (g + 1) - 2 * (g + 1) * (g + 1) <= sid) ++g;
    const int local = sid - (130 * g - 2 * g * g);
    const int v  = 32 - g;                 // segments per strip in this group
    const int r4 = local / v;              // which strip within the group
    const int s4 = local - r4 * v;         // segment index within the strip
    const int ti = 4 * g + r4;
    const int tj0 = ti + SEGT * s4;
    const int nt = (NTILE - tj0 < SEGT) ? (NTILE - tj0) : SEGT;

    __shared__ unsigned char Ls[65536];   // A: [0,32K) kh-major; B slot s at 32K+s*16K

    const int tid  = threadIdx.x;
    const int wave = tid >> 6;
    const int lane = tid & 63;
    const int wr = wave >> 1, wc = wave & 1;
    const int lm = lane & 15, lq = lane >> 4;

    // ---- staging lane geometry (width-16: 1KB instr = 8 rows x 8 granules)
    const int r8 = lane >> 3;                   // row within 8-row group
    const int pg = lane & 7;                    // LDS granule slot
    const int G0 = pg ^ (r8 >> 1);              // global granule, even instrs
    const int dlt = 64 - ((G0 & 4) << 5);       // odd instrs: granule G0^4
    const unsigned char* pA =
        Z + (size_t)(ti * BT + wave * 32 + r8) * DIM + (G0 << 4);
    const unsigned char* pB0 =
        Z + (size_t)(tj0 * BT + wave * 32 + r8) * DIM + (G0 << 4);

    auto stageB = [&](const unsigned char* pb, int kh, int sl) {
        #pragma unroll
        for (int c = 0; c < 4; ++c) {
            const unsigned char* gb = ((c & 1) ? pb + dlt : pb) + c * 2048 + kh * 128;
            __builtin_amdgcn_global_load_lds(
                (const __attribute__((address_space(1))) void*)gb,
                (__attribute__((address_space(3))) void*)
                    (Ls + 32768 + sl * 16384 + (wave * 4 + c) * 1024), 16, 0, 0);
        }
    };

    // prologue: full A panel (both K-halves) + B(tile0, kh0) -> slot0
    #pragma unroll
    for (int kh = 0; kh < 2; ++kh)
        #pragma unroll
        for (int c = 0; c < 4; ++c) {
            const unsigned char* ga = ((c & 1) ? pA + dlt : pA) + c * 2048 + kh * 128;
            __builtin_amdgcn_global_load_lds(
                (const __attribute__((address_space(1))) void*)ga,
                (__attribute__((address_space(3))) void*)
                    (Ls + kh * 16384 + (wave * 4 + c) * 1024), 16, 0, 0);
        }
    stageB(pB0, 0, 0);

    // ---- frag-read bases (invariant across the whole segment)
    const int s0 = (lq ^ (lm >> 1)) << 4;       // slot of granule lq
    const int s1 = s0 ^ 64;                     // slot of granule lq^4
    const unsigned char* LA = Ls + wr * 8192 + lm * 128;           // + kh*16K
    const unsigned char* LB = Ls + 32768 + wc * 8192 + lm * 128;   // + slot*16K

    const float SC = 2.8853900817779268f / 256.0f;   // exp(2*sim), dot=256*sim
    const int tiBase = ti * (257 - ti) / 2;

    for (int t = 0; t < nt; ++t) {
        f32x4 acc[4][4] = {};
        #pragma unroll
        for (int kh = 0; kh < 2; ++kh) {
            __syncthreads();    // drains stage(h) [one compute phase of cover]
            // prefetch next half into the slot whose readers just finished
            if (kh == 0)            stageB(pB0 + (size_t)t * 32768, 1, 1);
            else if (t + 1 < nt)    stageB(pB0 + (size_t)(t + 1) * 32768, 0, 0);

            const unsigned char* la = LA + (kh << 14);
            const unsigned char* lb = LB + (kh << 14);   // slot == kh
            lx2 aP[4], bP[4];
            __builtin_amdgcn_s_setprio(1);
            #pragma unroll
            for (int f = 0; f < 4; ++f) {
                aP[f] = *(const lx2*)(la + s0 + f * 2048);
                bP[f] = *(const lx2*)(lb + s0 + f * 2048);
            }
            #pragma unroll
            for (int fr = 0; fr < 4; ++fr)
                #pragma unroll
                for (int fc = 0; fc < 4; ++fc) {
                    acc[fr][fc] = __builtin_amdgcn_mfma_f32_16x16x32_fp8_fp8(
                        aP[fr].x, bP[fc].x, acc[fr][fc], 0, 0, 0);
                    acc[fr][fc] = __builtin_amdgcn_mfma_f32_16x16x32_fp8_fp8(
                        aP[fr].y, bP[fc].y, acc[fr][fc], 0, 0, 0);
                }
            #pragma unroll
            for (int f = 0; f < 4; ++f) {
                aP[f] = *(const lx2*)(la + s1 + f * 2048);
                bP[f] = *(const lx2*)(lb + s1 + f * 2048);
            }
            #pragma unroll
            for (int fr = 0; fr < 4; ++fr)
                #pragma unroll
                for (int fc = 0; fc < 4; ++fc) {
                    acc[fr][fc] = __builtin_amdgcn_mfma_f32_16x16x32_fp8_fp8(
                        aP[fr].x, bP[fc].x, acc[fr][fc], 0, 0, 0);
                    acc[fr][fc] = __builtin_amdgcn_mfma_f32_16x16x32_fp8_fp8(
                        aP[fr].y, bP[fc].y, acc[fr][fc], 0, 0, 0);
                }
            __builtin_amdgcn_s_setprio(0);
        }

        // ---- epilogue for tile (ti, tj) — LDS-free, overlaps in-flight stage
        #pragma unroll
        for (int fr = 0; fr < 4; ++fr)
            #pragma unroll
            for (int fc = 0; fc < 4; ++fc)
                #pragma unroll
                for (int r = 0; r < 4; ++r)
                    acc[fr][fc][r] = exp2f(acc[fr][fc][r] * SC);

        const int tj = tj0 + t;
        if (ti == tj) {   // zero at-or-below-diagonal (each pair counted once)
            #pragma unroll
            for (int fr = 0; fr < 4; ++fr) {
                const int gi = wr * 64 + fr * 16 + lq * 4;
                #pragma unroll
                for (int fc = 0; fc < 4; ++fc) {
                    const int gj = wc * 64 + fc * 16 + lm;
                    #pragma unroll
                    for (int r = 0; r < 4; ++r)
                        if (gj <= gi + r) acc[fr][fc][r] = 0.0f;
                }
            }
        }

        float* dst = TWO_STAGE ? (part + (size_t)(tiBase + (tj - ti)) * 512)
                               : nullptr;

        // row partials over this wave's 64 cols (C/D: col=lane&15, row=lq*4+r)
        // stored as float4: 4 lanes x 16B consecutive = one full 64B line
        #pragma unroll
        for (int fr = 0; fr < 4; ++fr) {
            f32x4 rs;
            #pragma unroll
            for (int r = 0; r < 4; ++r) {
                float s = acc[fr][0][r] + acc[fr][1][r] + acc[fr][2][r] + acc[fr][3][r];
                s += __shfl_xor(s, 1, 64);
                s += __shfl_xor(s, 2, 64);
                s += __shfl_xor(s, 4, 64);
                s += __shfl_xor(s, 8, 64);
                rs[r] = s;
            }
            if (lm == 0) {
                const int rr = wr * 64 + fr * 16 + lq * 4;
                if (TWO_STAGE) *(f32x4*)(dst + wc * 128 + rr) = rs;
                else {
                    #pragma unroll
                    for (int r = 0; r < 4; ++r)
                        atomicAdd(&S[ti * BT + rr + r], rs[r]);
                }
            }
        }
        // col partials over this wave's 64 rows (symmetry: colsum feeds S too)
        #pragma unroll
        for (int fc = 0; fc < 4; ++fc) {
            float s = 0.0f;
            #pragma unroll
            for (int fr = 0; fr < 4; ++fr)
                #pragma unroll
                for (int r = 0; r < 4; ++r) s += acc[fr][fc][r];
            s += __shfl_xor(s, 16, 64);
            s += __shfl_xor(s, 32, 64);
            if (lq == 0) {
                const int cc = wc * 64 + fc * 16 + lm;
                if (TWO_STAGE) dst[256 + wr * 128 + cc] = s;
                else atomicAdd(&S[tj * BT + cc], s);
            }
        }
    }
}

// ---------------------------------------------------------------------------
// Kernel 3: parallel partial gather. grid (NZ/256, NCHUNK). Each Z-row has
// exactly 258 strips: row-side blocks (tr,tj) tj=tr..127 (slots {0,128}+rr),
// col-side blocks (ti,tr) ti=0..tr (slots 256+{0,128}+rr). All coalesced.
// Also zeroes out[0].
// ---------------------------------------------------------------------------
__global__ __launch_bounds__(256) void reduce_kernel(
    const float* __restrict__ part, float* __restrict__ S2,
    float* __restrict__ out)
{
    const int chunk = blockIdx.y;
    const int tid = threadIdx.x;
    const int r = blockIdx.x * 256 + tid;       // Z row
    const int tr = r >> 7, rr = r & 127;
    const int baseRow = tr * (257 - tr) / 2;
    const int cntRow = 2 * (128 - tr);

    if (chunk == 0 && r == 0) out[0] = 0.0f;

    float s = 0.0f;
    for (int m = chunk; m < 258; m += NCHUNK) {
        size_t addr;
        if (m < cntRow) {
            const int bb = baseRow + (m >> 1);
            addr = (size_t)bb * 512 + (m & 1) * 128 + rr;
        } else {
            const int m2 = m - cntRow;
            const int tiq = m2 >> 1;
            const int bb = tiq * (257 - tiq) / 2 + (tr - tiq);
            addr = (size_t)bb * 512 + 256 + (m2 & 1) * 128 + rr;
        }
        s += part[addr];
    }
    S2[(size_t)chunk * NZ + r] = s;
}

// ---------------------------------------------------------------------------
// Kernel 4: loss + mean (two-stage path).
// ---------------------------------------------------------------------------
__global__ __launch_bounds__(256) void loss2_kernel(
    const float* __restrict__ S2, const float* __restrict__ pos,
    float* __restrict__ out)
{
    const int i = blockIdx.x * 256 + threadIdx.x;
    float den1 = 0.0f, den2 = 0.0f;
    #pragma unroll
    for (int c = 0; c < NCHUNK; ++c) {
        den1 += S2[(size_t)c * NZ + i];
        den2 += S2[(size_t)c * NZ + N_ROWS + i];
    }
    float v = 0.5f * (logf(den1) + logf(den2)) - TAU_INV * pos[i];

    __shared__ float red[4];
    #pragma unroll
    for (int m = 1; m < 64; m <<= 1) v += __shfl_xor(v, m, 64);
    if ((threadIdx.x & 63) == 0) red[threadIdx.x >> 6] = v;
    __syncthreads();
    if (threadIdx.x == 0)
        atomicAdd(out, (red[0] + red[1] + red[2] + red[3]) * (1.0f / N_ROWS));
}

// Fallback loss (atomic path, only if ws too small — never expected).
__global__ __launch_bounds__(256) void loss_kernel(
    const float* __restrict__ S, const float* __restrict__ pos,
    float* __restrict__ out)
{
    const int i = blockIdx.x * 256 + threadIdx.x;
    float v = 0.5f * (logf(S[i]) + logf(S[N_ROWS + i])) - TAU_INV * pos[i];

    __shared__ float red[4];
    #pragma unroll
    for (int m = 1; m < 64; m <<= 1) v += __shfl_xor(v, m, 64);
    if ((threadIdx.x & 63) == 0) red[threadIdx.x >> 6] = v;
    __syncthreads();
    if (threadIdx.x == 0)
        atomicAdd(out, (red[0] + red[1] + red[2] + red[3]) * (1.0f / N_ROWS));
}

// ---------------------------------------------------------------------------
extern "C" void kernel_launch(void* const* d_in, const int* in_sizes, int n_in,
                              void* d_out, int out_size, void* d_ws, size_t ws_size,
                              hipStream_t stream)
{
    const float* z1 = (const float*)d_in[0];
    const float* z2 = (const float*)d_in[1];
    float* out = (float*)d_out;

    char* ws = (char*)d_ws;
    unsigned char* Z8 = (unsigned char*)ws;              // 16384*256 = 4 MB
    float* pos  = (float*)(ws + 4194304);                // 32 KB
    float* S2   = (float*)(ws + 4227072);                // 16*16384*4 = 1 MB
    float* part = (float*)(ws + 5275648);                // 8256*512*4 = 16.9 MB
    const size_t need = 5275648 + (size_t)NTRI * 512 * 4;

    normalize_kernel<<<N_ROWS / 4, 256, 0, stream>>>(z1, z2, Z8, pos);

    if (ws_size >= need) {
        gram_kernel<true><<<NSEG, 256, 0, stream>>>(Z8, part, nullptr);
        dim3 rg(NZ / 256, NCHUNK);
        reduce_kernel<<<rg, 256, 0, stream>>>(part, S2, out);   // zeroes out
        loss2_kernel<<<N_ROWS / 256, 256, 0, stream>>>(S2, pos, out);
    } else {
        hipMemsetAsync(S2, 0, NZ * sizeof(float), stream);
        hipMemsetAsync(out, 0, sizeof(float), stream);
        gram_kernel<false><<<NSEG, 256, 0, stream>>>(Z8, nullptr, S2);
        loss_kernel<<<N_ROWS / 256, 256, 0, stream>>>(S2, pos, out);
    }
}

// Round 3
// 157.517 us; speedup vs baseline: 1.1396x; 1.1396x over previous
//
#include <hip/hip_runtime.h>
#include <hip/hip_bf16.h>
#include <hip/hip_fp8.h>

#define N_ROWS 8192
#define NZ 16384           // rows of Z = [An; Bn]
#define DIM 256
#define TAU_INV 2.0f
#define BT 128             // col tile width
#define AT 64              // row tile height (A strip)
#define NTILE 128          // NZ / BT  (col tiles)
#define NRI 256            // NZ / AT  (row strips)
#define NCHUNK 16
#define SEGT 4             // col tiles per segment
#define NSEG 4224          // sum over ri of ceil((128 - (ri>>1))/4)
#define PSTRIDE 1152       // floats/segment: 128 row-partials + 4*256 col-partials

typedef float f32x4 __attribute__((ext_vector_type(4)));
typedef long lx2 __attribute__((ext_vector_type(2)));   // 16B = 2 fp8 MFMA operands

// ---------------------------------------------------------------------------
// Kernel 1: one WAVE per row. L2-normalize, scale by 16, quantize to OCP fp8
// e4m3, write Z8 K-INTERLEAVED: each 64B chunk stores its eight 8B K-groups
// as [g0 g4 g1 g5 g2 g6 g3 g7] so one 16B granule = operand pair (g, g+4)
// for two consecutive MFMA K-steps. pos[i] = (1/256)*dot(quantized an, bn).
// ---------------------------------------------------------------------------
__global__ __launch_bounds__(256) void normalize_kernel(
    const float* __restrict__ z1, const float* __restrict__ z2,
    unsigned char* __restrict__ Z8, float* __restrict__ pos)
{
    const int tid = threadIdx.x;
    const int wave = tid >> 6;
    const int lane = tid & 63;
    const int row = blockIdx.x * 4 + wave;      // 0..8191

    const float4 a = ((const float4*)(z1 + (size_t)row * DIM))[lane];
    const float4 b = ((const float4*)(z2 + (size_t)row * DIM))[lane];

    auto wsum = [&](float v) -> float {
        #pragma unroll
        for (int m = 1; m < 64; m <<= 1) v += __shfl_xor(v, m, 64);
        return v;
    };

    const float na2 = wsum(a.x*a.x + a.y*a.y + a.z*a.z + a.w*a.w);
    const float nb2 = wsum(b.x*b.x + b.y*b.y + b.z*b.z + b.w*b.w);
    const float sa = 16.0f / sqrtf(na2);   // norms ~16; eps never binds
    const float sb = 16.0f / sqrtf(nb2);

    const float av[4] = {a.x*sa, a.y*sa, a.z*sa, a.w*sa};
    const float bv[4] = {b.x*sb, b.y*sb, b.z*sb, b.w*sb};
    unsigned char pa[4], pb[4];
    float qd = 0.0f;
    #pragma unroll
    for (int k = 0; k < 4; ++k) {
        __hip_fp8_e4m3 qa(av[k]);
        __hip_fp8_e4m3 qb(bv[k]);
        pa[k] = qa.__x; pb[k] = qb.__x;
        qd += float(qa) * float(qb);
    }
    const int g  = (lane >> 1) & 7;
    const int pp = ((g & 3) << 1) | (g >> 2);          // interleaved 8B slot
    const int off = (lane >> 4) * 64 + pp * 8 + (lane & 1) * 4;
    *(uchar4*)(Z8 + (size_t)row * DIM + off) = *(uchar4*)pa;
    *(uchar4*)(Z8 + (size_t)(N_ROWS + row) * DIM + off) = *(uchar4*)pb;

    qd = wsum(qd);
    if (lane == 0) pos[row] = qd * 0.00390625f;   // /256 -> quantized sim
}

// ---------------------------------------------------------------------------
// Kernel 2: symmetric fp8 gram, upper triangle, 64x128 tiles, STRIP-SEGMENTED.
// Block owns one 64-row strip segment of up to SEGT=4 col tiles:
//   - A strip (64 rows x 256B, both K-halves) = 16 KB, staged once/segment
//   - B half-panels (16 KB) stream through a 2-slot ring, prefetched one
//     phase ahead (issue right after the barrier, drained by the next one —
//     a full 32-MFMA compute phase + epilogue of cover).
// LDS = 48 KB -> 3 blocks/CU (R2 lesson: 64 KB halved occupancy and lost).
// Row partials accumulate in REGISTERS across the segment; the cross-lane
// reduce + store runs once per segment (R2 lesson: per-tile epilogue VALU
// was a co-equal cost bucket with MFMA). Col partials per tile (different B).
// Same proven 16B-granule XOR swizzle (conflicts measured 0), b128 frag
// reads, interleaved staging, full-64B-line float stores.
// ---------------------------------------------------------------------------
template <bool TWO_STAGE>
__global__ __launch_bounds__(256, 3) void gram_kernel(
    const unsigned char* __restrict__ Z,
    float* __restrict__ part, float* __restrict__ S)
{
    // XCD band remap over segments (4224 = 8 * 528), then segment decode.
    const int sid = (blockIdx.x & 7) * (NSEG / 8) + (blockIdx.x >> 3);
    // group g: strips ri = 8g..8g+7 each have v = 32-g segments;
    // cum(g) = 260g - 4g^2 segments before group g.
    int g = (int)((260.0f - sqrtf(67600.0f - 16.0f * (float)sid)) * 0.125f);
    g = g < 0 ? 0 : (g > 31 ? 31 : g);
    while (260 * g - 4 * g * g > sid) --g;
    while (g < 31 && 260 * (g + 1) - 4 * (g + 1) * (g + 1) <= sid) ++g;
    const int local = sid - (260 * g - 4 * g * g);
    const int v  = 32 - g;                 // segments per strip in this group
    const int r8i = local / v;
    const int s4 = local - r8i * v;
    const int ri = 8 * g + r8i;            // row strip 0..255
    const int tj0 = (ri >> 1) + SEGT * s4; // first col tile
    const int nt = (NTILE - tj0 < SEGT) ? (NTILE - tj0) : SEGT;

    __shared__ unsigned char Ls[49152];   // A[kh][64][128] 16K; B slot s at 16K+s*16K

    const int tid  = threadIdx.x;
    const int wave = tid >> 6;
    const int lane = tid & 63;
    const int wr = wave >> 1, wc = wave & 1;   // wave grid 2x2 over 64x128
    const int lm = lane & 15, lq = lane >> 4;

    // ---- staging lane geometry (width-16: 1KB instr = 8 rows x 8 granules)
    const int r8 = lane >> 3;                   // row within 8-row group
    const int pg = lane & 7;                    // LDS granule slot
    const int G0 = pg ^ (r8 >> 1);              // global granule, even instrs
    const int dlt = 64 - ((G0 & 4) << 5);       // odd instrs: granule G0^4
    const unsigned char* pA =
        Z + (size_t)(ri * AT + wave * 16 + r8) * DIM + (G0 << 4);
    const unsigned char* pB0 =
        Z + (size_t)(tj0 * BT + wave * 32 + r8) * DIM + (G0 << 4);

    auto stageB = [&](const unsigned char* pb, int kh, int sl) {
        #pragma unroll
        for (int c = 0; c < 4; ++c) {           // rows wave*32 + c*8 + r8
            const unsigned char* gb = ((c & 1) ? pb + dlt : pb) + c * 2048 + kh * 128;
            __builtin_amdgcn_global_load_lds(
                (const __attribute__((address_space(1))) void*)gb,
                (__attribute__((address_space(3))) void*)
                    (Ls + 16384 + sl * 16384 + (wave * 4 + c) * 1024), 16, 0, 0);
        }
    };

    // prologue: A strip (both K-halves, rows wave*16 + c*8 + r8) + B(t0,kh0)
    #pragma unroll
    for (int kh = 0; kh < 2; ++kh)
        #pragma unroll
        for (int c = 0; c < 2; ++c) {
            const unsigned char* ga = ((c & 1) ? pA + dlt : pA) + c * 2048 + kh * 128;
            __builtin_amdgcn_global_load_lds(
                (const __attribute__((address_space(1))) void*)ga,
                (__attribute__((address_space(3))) void*)
                    (Ls + kh * 8192 + wave * 2048 + c * 1024), 16, 0, 0);
        }
    stageB(pB0, 0, 0);

    // ---- frag-read bases (invariant across the whole segment)
    const int s0 = (lq ^ (lm >> 1)) << 4;       // slot of granule lq
    const int s1 = s0 ^ 64;                     // slot of granule lq^4
    const unsigned char* LA = Ls + (wr * 32 + lm) * 128;           // + kh*8192
    const unsigned char* LB = Ls + 16384 + (wc * 64 + lm) * 128;   // + slot*16K

    const float SC = 2.8853900817779268f / 256.0f;   // exp(2*sim), dot=256*sim

    f32x4 rowacc[2] = {};   // per-lane row partial, accumulated over segment

    for (int t = 0; t < nt; ++t) {
        f32x4 acc[2][4] = {};
        #pragma unroll
        for (int kh = 0; kh < 2; ++kh) {
            __syncthreads();    // drains stage(h) [one compute phase of cover]
            if (kh == 0)            stageB(pB0 + (size_t)t * 32768, 1, 1);
            else if (t + 1 < nt)    stageB(pB0 + (size_t)(t + 1) * 32768, 0, 0);

            const unsigned char* la = LA + (kh << 13);
            const unsigned char* lb = LB + (kh << 14);   // slot == kh
            lx2 aP[2], bP[4];
            __builtin_amdgcn_s_setprio(1);
            #pragma unroll
            for (int f = 0; f < 2; ++f) aP[f] = *(const lx2*)(la + s0 + f * 2048);
            #pragma unroll
            for (int f = 0; f < 4; ++f) bP[f] = *(const lx2*)(lb + s0 + f * 2048);
            #pragma unroll
            for (int fr = 0; fr < 2; ++fr)
                #pragma unroll
                for (int fc = 0; fc < 4; ++fc) {
                    acc[fr][fc] = __builtin_amdgcn_mfma_f32_16x16x32_fp8_fp8(
                        aP[fr].x, bP[fc].x, acc[fr][fc], 0, 0, 0);
                    acc[fr][fc] = __builtin_amdgcn_mfma_f32_16x16x32_fp8_fp8(
                        aP[fr].y, bP[fc].y, acc[fr][fc], 0, 0, 0);
                }
            #pragma unroll
            for (int f = 0; f < 2; ++f) aP[f] = *(const lx2*)(la + s1 + f * 2048);
            #pragma unroll
            for (int f = 0; f < 4; ++f) bP[f] = *(const lx2*)(lb + s1 + f * 2048);
            #pragma unroll
            for (int fr = 0; fr < 2; ++fr)
                #pragma unroll
                for (int fc = 0; fc < 4; ++fc) {
                    acc[fr][fc] = __builtin_amdgcn_mfma_f32_16x16x32_fp8_fp8(
                        aP[fr].x, bP[fc].x, acc[fr][fc], 0, 0, 0);
                    acc[fr][fc] = __builtin_amdgcn_mfma_f32_16x16x32_fp8_fp8(
                        aP[fr].y, bP[fc].y, acc[fr][fc], 0, 0, 0);
                }
            __builtin_amdgcn_s_setprio(0);
        }

        // ---- per-tile epilogue (LDS-free; overlaps in-flight stage)
        #pragma unroll
        for (int fr = 0; fr < 2; ++fr)
            #pragma unroll
            for (int fc = 0; fc < 4; ++fc)
                #pragma unroll
                for (int r = 0; r < 4; ++r)
                    acc[fr][fc][r] = exp2f(acc[fr][fc][r] * SC);

        const int tj = tj0 + t;
        if (tj == (ri >> 1)) {   // only tile of the segment crossing diagonal
            const int add = (ri & 1) << 6;    // odd strip: rows sit 64 below
            #pragma unroll
            for (int fr = 0; fr < 2; ++fr) {
                const int ciloc = wr * 32 + fr * 16 + lq * 4;
                #pragma unroll
                for (int fc = 0; fc < 4; ++fc) {
                    const int cj = wc * 64 + fc * 16 + lm;
                    #pragma unroll
                    for (int r = 0; r < 4; ++r)
                        if (cj <= ciloc + r + add) acc[fr][fc][r] = 0.0f;
                }
            }
        }

        // row partials: accumulate in registers across the segment
        #pragma unroll
        for (int fr = 0; fr < 2; ++fr)
            #pragma unroll
            for (int r = 0; r < 4; ++r)
                rowacc[fr][r] += acc[fr][0][r] + acc[fr][1][r]
                               + acc[fr][2][r] + acc[fr][3][r];

        // col partials per tile (B changes each tile)
        float* dstc = TWO_STAGE ? (part + (size_t)sid * PSTRIDE + 128 + t * 256)
                                : nullptr;
        #pragma unroll
        for (int fc = 0; fc < 4; ++fc) {
            float s = 0.0f;
            #pragma unroll
            for (int fr = 0; fr < 2; ++fr)
                #pragma unroll
                for (int r = 0; r < 4; ++r) s += acc[fr][fc][r];
            s += __shfl_xor(s, 16, 64);
            s += __shfl_xor(s, 32, 64);
            if (lq == 0) {      // 16 lanes x 4B consecutive = full 64B line
                const int cc = wc * 64 + fc * 16 + lm;
                if (TWO_STAGE) dstc[wr * 128 + cc] = s;
                else atomicAdd(&S[tj * BT + cc], s);
            }
        }
    }

    // ---- segment epilogue: lane-reduce + store row partials ONCE
    float* dstr = TWO_STAGE ? (part + (size_t)sid * PSTRIDE) : nullptr;
    #pragma unroll
    for (int fr = 0; fr < 2; ++fr) {
        f32x4 rs;
        #pragma unroll
        for (int r = 0; r < 4; ++r) {
            float s = rowacc[fr][r];
            s += __shfl_xor(s, 1, 64);
            s += __shfl_xor(s, 2, 64);
            s += __shfl_xor(s, 4, 64);
            s += __shfl_xor(s, 8, 64);
            rs[r] = s;
        }
        if (lm == 0) {          // 4 lanes x 16B consecutive = full 64B line
            const int rr = wr * 32 + fr * 16 + lq * 4;
            if (TWO_STAGE) *(f32x4*)(dstr + wc * 64 + rr) = rs;
            else {
                #pragma unroll
                for (int r = 0; r < 4; ++r)
                    atomicAdd(&S[ri * AT + rr + r], rs[r]);
            }
        }
    }
}

// ---------------------------------------------------------------------------
// Kernel 3: parallel partial gather. grid (NZ/256, NCHUNK).
// Row r: row-side = every segment of strip ri=r>>6 (2 entries each, wc 0/1);
// col-side = every strip rip = 0..2*tj+1 hitting col tile tj=r>>7 (2 entries,
// wr 0/1). All reads coalesced (64-lane runs share ri / tj). Zeroes out[0].
// ---------------------------------------------------------------------------
__global__ __launch_bounds__(256) void reduce_kernel(
    const float* __restrict__ part, float* __restrict__ S2,
    float* __restrict__ out)
{
    const int chunk = blockIdx.y;
    const int tid = threadIdx.x;
    const int r = blockIdx.x * 256 + tid;       // Z row
    const int ri = r >> 6, rr = r & 63;
    const int gg = ri >> 3;
    const int nseg = 32 - gg;
    const int sid0 = 260 * gg - 4 * gg * gg + (ri & 7) * nseg;
    const int tj = r >> 7, cc = r & 127;
    const int nr = 2 * tj + 2;                  // strips covering col tile tj
    const int T = 2 * nseg + 2 * nr;

    if (chunk == 0 && r == 0) out[0] = 0.0f;

    float s = 0.0f;
    for (int m = chunk; m < T; m += NCHUNK) {
        size_t addr;
        if (m < 2 * nseg) {
            const int sg = m >> 1;              // segment within strip
            addr = (size_t)(sid0 + sg) * PSTRIDE + (m & 1) * 64 + rr;
        } else {
            const int m2 = m - 2 * nseg;
            const int rip = m2 >> 1;            // source strip
            const int dtj = tj - (rip >> 1);
            const int gp = rip >> 3;
            const int sidc = 260 * gp - 4 * gp * gp + (rip & 7) * (32 - gp)
                           + (dtj >> 2);
            addr = (size_t)sidc * PSTRIDE + 128 + (dtj & 3) * 256
                 + (m2 & 1) * 128 + cc;
        }
        s += part[addr];
    }
    S2[(size_t)chunk * NZ + r] = s;
}

// ---------------------------------------------------------------------------
// Kernel 4: loss + mean (two-stage path).
// ---------------------------------------------------------------------------
__global__ __launch_bounds__(256) void loss2_kernel(
    const float* __restrict__ S2, const float* __restrict__ pos,
    float* __restrict__ out)
{
    const int i = blockIdx.x * 256 + threadIdx.x;
    float den1 = 0.0f, den2 = 0.0f;
    #pragma unroll
    for (int c = 0; c < NCHUNK; ++c) {
        den1 += S2[(size_t)c * NZ + i];
        den2 += S2[(size_t)c * NZ + N_ROWS + i];
    }
    float v = 0.5f * (logf(den1) + logf(den2)) - TAU_INV * pos[i];

    __shared__ float red[4];
    #pragma unroll
    for (int m = 1; m < 64; m <<= 1) v += __shfl_xor(v, m, 64);
    if ((threadIdx.x & 63) == 0) red[threadIdx.x >> 6] = v;
    __syncthreads();
    if (threadIdx.x == 0)
        atomicAdd(out, (red[0] + red[1] + red[2] + red[3]) * (1.0f / N_ROWS));
}

// Fallback loss (atomic path, only if ws too small — never expected).
__global__ __launch_bounds__(256) void loss_kernel(
    const float* __restrict__ S, const float* __restrict__ pos,
    float* __restrict__ out)
{
    const int i = blockIdx.x * 256 + threadIdx.x;
    float v = 0.5f * (logf(S[i]) + logf(S[N_ROWS + i])) - TAU_INV * pos[i];

    __shared__ float red[4];
    #pragma unroll
    for (int m = 1; m < 64; m <<= 1) v += __shfl_xor(v, m, 64);
    if ((threadIdx.x & 63) == 0) red[threadIdx.x >> 6] = v;
    __syncthreads();
    if (threadIdx.x == 0)
        atomicAdd(out, (red[0] + red[1] + red[2] + red[3]) * (1.0f / N_ROWS));
}

// ---------------------------------------------------------------------------
extern "C" void kernel_launch(void* const* d_in, const int* in_sizes, int n_in,
                              void* d_out, int out_size, void* d_ws, size_t ws_size,
                              hipStream_t stream)
{
    const float* z1 = (const float*)d_in[0];
    const float* z2 = (const float*)d_in[1];
    float* out = (float*)d_out;

    char* ws = (char*)d_ws;
    unsigned char* Z8 = (unsigned char*)ws;              // 16384*256 = 4 MB
    float* pos  = (float*)(ws + 4194304);                // 32 KB
    float* S2   = (float*)(ws + 4227072);                // 16*16384*4 = 1 MB
    float* part = (float*)(ws + 5275648);                // 4224*1152*4 = 19.5 MB
    const size_t need = 5275648 + (size_t)NSEG * PSTRIDE * 4;

    normalize_kernel<<<N_ROWS / 4, 256, 0, stream>>>(z1, z2, Z8, pos);

    if (ws_size >= need) {
        gram_kernel<true><<<NSEG, 256, 0, stream>>>(Z8, part, nullptr);
        dim3 rg(NZ / 256, NCHUNK);
        reduce_kernel<<<rg, 256, 0, stream>>>(part, S2, out);   // zeroes out
        loss2_kernel<<<N_ROWS / 256, 256, 0, stream>>>(S2, pos, out);
    } else {
        hipMemsetAsync(S2, 0, NZ * sizeof(float), stream);
        hipMemsetAsync(out, 0, sizeof(float), stream);
        gram_kernel<false><<<NSEG, 256, 0, stream>>>(Z8, nullptr, S2);
        loss_kernel<<<N_ROWS / 256, 256, 0, stream>>>(S2, pos, out);
    }
}

// Round 4
// 153.942 us; speedup vs baseline: 1.1661x; 1.0232x over previous
//
#include <hip/hip_runtime.h>
#include <hip/hip_bf16.h>
#include <hip/hip_fp8.h>

#define N_ROWS 8192
#define NZ 16384           // rows of Z = [An; Bn]
#define DIM 256
#define TAU_INV 2.0f
#define BT 128             // col tile width
#define AT 64              // row tile height (A strip)
#define NTILE 128          // NZ / BT  (col tiles)
#define NRI 256            // NZ / AT  (row strips)
#define NCHUNK 16
#define SEGT 4             // col tiles per segment
#define NSEG 4224          // sum over ri of ceil((128 - (ri>>1))/4)
#define PSTRIDE 1152       // floats/segment: 128 row-partials + 4*256 col-partials

typedef float f32x4 __attribute__((ext_vector_type(4)));
typedef long lx2 __attribute__((ext_vector_type(2)));   // 16B = 2 fp8 MFMA operands

// ---------------------------------------------------------------------------
// Kernel 1: one WAVE per row. L2-normalize, scale by 16, quantize to OCP fp8
// e4m3, write Z8 K-INTERLEAVED: each 64B chunk stores its eight 8B K-groups
// as [g0 g4 g1 g5 g2 g6 g3 g7] so one 16B granule = operand pair (g, g+4)
// for two consecutive MFMA K-steps. pos[i] = (1/256)*dot(quantized an, bn).
// ---------------------------------------------------------------------------
__global__ __launch_bounds__(256) void normalize_kernel(
    const float* __restrict__ z1, const float* __restrict__ z2,
    unsigned char* __restrict__ Z8, float* __restrict__ pos)
{
    const int tid = threadIdx.x;
    const int wave = tid >> 6;
    const int lane = tid & 63;
    const int row = blockIdx.x * 4 + wave;      // 0..8191

    const float4 a = ((const float4*)(z1 + (size_t)row * DIM))[lane];
    const float4 b = ((const float4*)(z2 + (size_t)row * DIM))[lane];

    auto wsum = [&](float v) -> float {
        #pragma unroll
        for (int m = 1; m < 64; m <<= 1) v += __shfl_xor(v, m, 64);
        return v;
    };

    const float na2 = wsum(a.x*a.x + a.y*a.y + a.z*a.z + a.w*a.w);
    const float nb2 = wsum(b.x*b.x + b.y*b.y + b.z*b.z + b.w*b.w);
    const float sa = 16.0f / sqrtf(na2);   // norms ~16; eps never binds
    const float sb = 16.0f / sqrtf(nb2);

    const float av[4] = {a.x*sa, a.y*sa, a.z*sa, a.w*sa};
    const float bv[4] = {b.x*sb, b.y*sb, b.z*sb, b.w*sb};
    unsigned char pa[4], pb[4];
    float qd = 0.0f;
    #pragma unroll
    for (int k = 0; k < 4; ++k) {
        __hip_fp8_e4m3 qa(av[k]);
        __hip_fp8_e4m3 qb(bv[k]);
        pa[k] = qa.__x; pb[k] = qb.__x;
        qd += float(qa) * float(qb);
    }
    const int g  = (lane >> 1) & 7;
    const int pp = ((g & 3) << 1) | (g >> 2);          // interleaved 8B slot
    const int off = (lane >> 4) * 64 + pp * 8 + (lane & 1) * 4;
    *(uchar4*)(Z8 + (size_t)row * DIM + off) = *(uchar4*)pa;
    *(uchar4*)(Z8 + (size_t)(N_ROWS + row) * DIM + off) = *(uchar4*)pb;

    qd = wsum(qd);
    if (lane == 0) pos[row] = qd * 0.00390625f;   // /256 -> quantized sim
}

// ---------------------------------------------------------------------------
// Kernel 2: symmetric fp8 gram, upper triangle, 64x128 tiles, STRIP-SEGMENTED,
// A-IN-REGISTERS (R4): A fragments are tile-invariant across the segment, so
// a prologue stages the A strip into the (not-yet-live) B-ring LDS, each wave
// copies its 8 lx2 A frags to VGPRs (32 regs), and the steady-state loop only
// touches LDS for B. LDS drops 48->32 KB => 4 blocks/CU (16 waves/CU, was 12;
// R3 lesson: the 90k stall cyc/SIMD needs more TLP), and per-tile ds_reads
// drop 24->16 b128. B half-panels stream through the 2-slot ring prefetched
// one phase ahead (2 barriers/tile, every stage covered by a 32-MFMA phase).
// Row partials accumulate in registers across the segment (R3); col partials
// per tile; full-64B-line stores; proven swizzle (conflicts measured 0).
// ---------------------------------------------------------------------------
template <bool TWO_STAGE>
__global__ __launch_bounds__(256, 4) void gram_kernel(
    const unsigned char* __restrict__ Z,
    float* __restrict__ part, float* __restrict__ S)
{
    // XCD band remap over segments (4224 = 8 * 528), then segment decode.
    const int sid = (blockIdx.x & 7) * (NSEG / 8) + (blockIdx.x >> 3);
    // group g: strips ri = 8g..8g+7 each have v = 32-g segments;
    // cum(g) = 260g - 4g^2 segments before group g.
    int g = (int)((260.0f - sqrtf(67600.0f - 16.0f * (float)sid)) * 0.125f);
    g = g < 0 ? 0 : (g > 31 ? 31 : g);
    while (260 * g - 4 * g * g > sid) --g;
    while (g < 31 && 260 * (g + 1) - 4 * (g + 1) * (g + 1) <= sid) ++g;
    const int local = sid - (260 * g - 4 * g * g);
    const int v  = 32 - g;                 // segments per strip in this group
    const int r8i = local / v;
    const int s4 = local - r8i * v;
    const int ri = 8 * g + r8i;            // row strip 0..255
    const int tj0 = (ri >> 1) + SEGT * s4; // first col tile
    const int nt = (NTILE - tj0 < SEGT) ? (NTILE - tj0) : SEGT;

    __shared__ unsigned char Ls[32768];   // B ring slots 0/1; prologue borrows it for A

    const int tid  = threadIdx.x;
    const int wave = tid >> 6;
    const int lane = tid & 63;
    const int wr = wave >> 1, wc = wave & 1;   // wave grid 2x2 over 64x128
    const int lm = lane & 15, lq = lane >> 4;

    // ---- staging lane geometry (width-16: 1KB instr = 8 rows x 8 granules)
    const int r8 = lane >> 3;                   // row within 8-row group
    const int pg = lane & 7;                    // LDS granule slot
    const int G0 = pg ^ (r8 >> 1);              // global granule, even instrs
    const int dlt = 64 - ((G0 & 4) << 5);       // odd instrs: granule G0^4
    const unsigned char* pA =
        Z + (size_t)(ri * AT + wave * 16 + r8) * DIM + (G0 << 4);
    const unsigned char* pB0 =
        Z + (size_t)(tj0 * BT + wave * 32 + r8) * DIM + (G0 << 4);

    auto stageB = [&](const unsigned char* pb, int kh, int sl) {
        #pragma unroll
        for (int c = 0; c < 4; ++c) {           // rows wave*32 + c*8 + r8
            const unsigned char* gb = ((c & 1) ? pb + dlt : pb) + c * 2048 + kh * 128;
            __builtin_amdgcn_global_load_lds(
                (const __attribute__((address_space(1))) void*)gb,
                (__attribute__((address_space(3))) void*)
                    (Ls + sl * 16384 + (wave * 4 + c) * 1024), 16, 0, 0);
        }
    };

    // ---- prologue: stage A strip (both K-halves) into [0,16K), read frags
    #pragma unroll
    for (int kh = 0; kh < 2; ++kh)
        #pragma unroll
        for (int c = 0; c < 2; ++c) {
            const unsigned char* ga = ((c & 1) ? pA + dlt : pA) + c * 2048 + kh * 128;
            __builtin_amdgcn_global_load_lds(
                (const __attribute__((address_space(1))) void*)ga,
                (__attribute__((address_space(3))) void*)
                    (Ls + kh * 8192 + wave * 2048 + c * 1024), 16, 0, 0);
        }
    __syncthreads();   // A staged (vmcnt+lgkm drained)

    const int s0 = (lq ^ (lm >> 1)) << 4;       // slot of granule lq
    const int s1 = s0 ^ 64;                     // slot of granule lq^4
    lx2 aR[2][2][2];                            // [kh][set][frag] — 32 VGPRs
    #pragma unroll
    for (int kh = 0; kh < 2; ++kh) {
        const unsigned char* la = Ls + (kh << 13) + (wr * 32 + lm) * 128;
        #pragma unroll
        for (int f = 0; f < 2; ++f) {
            aR[kh][0][f] = *(const lx2*)(la + s0 + f * 2048);
            aR[kh][1][f] = *(const lx2*)(la + s1 + f * 2048);
        }
    }
    __syncthreads();   // all waves done reading A before B overwrites slot 0
    stageB(pB0, 0, 0);

    // ---- B frag-read base (invariant across the segment)
    const unsigned char* LB = Ls + (wc * 64 + lm) * 128;   // + slot*16K

    const float SC = 2.8853900817779268f / 256.0f;   // exp(2*sim), dot=256*sim

    f32x4 rowacc[2] = {};   // per-lane row partial, accumulated over segment

    for (int t = 0; t < nt; ++t) {
        f32x4 acc[2][4] = {};
        #pragma unroll
        for (int kh = 0; kh < 2; ++kh) {
            __syncthreads();    // drains stage(h) [one compute phase of cover]
            if (kh == 0)            stageB(pB0 + (size_t)t * 32768, 1, 1);
            else if (t + 1 < nt)    stageB(pB0 + (size_t)(t + 1) * 32768, 0, 0);

            const unsigned char* lb = LB + (kh << 14);   // slot == kh
            lx2 bP[4];
            __builtin_amdgcn_s_setprio(1);
            #pragma unroll
            for (int f = 0; f < 4; ++f) bP[f] = *(const lx2*)(lb + s0 + f * 2048);
            #pragma unroll
            for (int fr = 0; fr < 2; ++fr)
                #pragma unroll
                for (int fc = 0; fc < 4; ++fc) {
                    acc[fr][fc] = __builtin_amdgcn_mfma_f32_16x16x32_fp8_fp8(
                        aR[kh][0][fr].x, bP[fc].x, acc[fr][fc], 0, 0, 0);
                    acc[fr][fc] = __builtin_amdgcn_mfma_f32_16x16x32_fp8_fp8(
                        aR[kh][0][fr].y, bP[fc].y, acc[fr][fc], 0, 0, 0);
                }
            #pragma unroll
            for (int f = 0; f < 4; ++f) bP[f] = *(const lx2*)(lb + s1 + f * 2048);
            #pragma unroll
            for (int fr = 0; fr < 2; ++fr)
                #pragma unroll
                for (int fc = 0; fc < 4; ++fc) {
                    acc[fr][fc] = __builtin_amdgcn_mfma_f32_16x16x32_fp8_fp8(
                        aR[kh][1][fr].x, bP[fc].x, acc[fr][fc], 0, 0, 0);
                    acc[fr][fc] = __builtin_amdgcn_mfma_f32_16x16x32_fp8_fp8(
                        aR[kh][1][fr].y, bP[fc].y, acc[fr][fc], 0, 0, 0);
                }
            __builtin_amdgcn_s_setprio(0);
        }

        // ---- per-tile epilogue (LDS-free; overlaps in-flight stage)
        #pragma unroll
        for (int fr = 0; fr < 2; ++fr)
            #pragma unroll
            for (int fc = 0; fc < 4; ++fc)
                #pragma unroll
                for (int r = 0; r < 4; ++r)
                    acc[fr][fc][r] = exp2f(acc[fr][fc][r] * SC);

        const int tj = tj0 + t;
        if (tj == (ri >> 1)) {   // only tile of the segment crossing diagonal
            const int add = (ri & 1) << 6;    // odd strip: rows sit 64 below
            #pragma unroll
            for (int fr = 0; fr < 2; ++fr) {
                const int ciloc = wr * 32 + fr * 16 + lq * 4;
                #pragma unroll
                for (int fc = 0; fc < 4; ++fc) {
                    const int cj = wc * 64 + fc * 16 + lm;
                    #pragma unroll
                    for (int r = 0; r < 4; ++r)
                        if (cj <= ciloc + r + add) acc[fr][fc][r] = 0.0f;
                }
            }
        }

        // row partials: accumulate in registers across the segment
        #pragma unroll
        for (int fr = 0; fr < 2; ++fr)
            #pragma unroll
            for (int r = 0; r < 4; ++r)
                rowacc[fr][r] += acc[fr][0][r] + acc[fr][1][r]
                               + acc[fr][2][r] + acc[fr][3][r];

        // col partials per tile (B changes each tile)
        float* dstc = TWO_STAGE ? (part + (size_t)sid * PSTRIDE + 128 + t * 256)
                                : nullptr;
        #pragma unroll
        for (int fc = 0; fc < 4; ++fc) {
            float s = 0.0f;
            #pragma unroll
            for (int fr = 0; fr < 2; ++fr)
                #pragma unroll
                for (int r = 0; r < 4; ++r) s += acc[fr][fc][r];
            s += __shfl_xor(s, 16, 64);
            s += __shfl_xor(s, 32, 64);
            if (lq == 0) {      // 16 lanes x 4B consecutive = full 64B line
                const int cc = wc * 64 + fc * 16 + lm;
                if (TWO_STAGE) dstc[wr * 128 + cc] = s;
                else atomicAdd(&S[tj * BT + cc], s);
            }
        }
    }

    // ---- segment epilogue: lane-reduce + store row partials ONCE
    float* dstr = TWO_STAGE ? (part + (size_t)sid * PSTRIDE) : nullptr;
    #pragma unroll
    for (int fr = 0; fr < 2; ++fr) {
        f32x4 rs;
        #pragma unroll
        for (int r = 0; r < 4; ++r) {
            float s = rowacc[fr][r];
            s += __shfl_xor(s, 1, 64);
            s += __shfl_xor(s, 2, 64);
            s += __shfl_xor(s, 4, 64);
            s += __shfl_xor(s, 8, 64);
            rs[r] = s;
        }
        if (lm == 0) {          // 4 lanes x 16B consecutive = full 64B line
            const int rr = wr * 32 + fr * 16 + lq * 4;
            if (TWO_STAGE) *(f32x4*)(dstr + wc * 64 + rr) = rs;
            else {
                #pragma unroll
                for (int r = 0; r < 4; ++r)
                    atomicAdd(&S[ri * AT + rr + r], rs[r]);
            }
        }
    }
}

// ---------------------------------------------------------------------------
// Kernel 3: parallel partial gather. grid (NZ/256, NCHUNK).
// Row r: row-side = every segment of strip ri=r>>6 (2 entries each, wc 0/1);
// col-side = every strip rip = 0..2*tj+1 hitting col tile tj=r>>7 (2 entries,
// wr 0/1). All reads coalesced (64-lane runs share ri / tj). Zeroes out[0].
// ---------------------------------------------------------------------------
__global__ __launch_bounds__(256) void reduce_kernel(
    const float* __restrict__ part, float* __restrict__ S2,
    float* __restrict__ out)
{
    const int chunk = blockIdx.y;
    const int tid = threadIdx.x;
    const int r = blockIdx.x * 256 + tid;       // Z row
    const int ri = r >> 6, rr = r & 63;
    const int gg = ri >> 3;
    const int nseg = 32 - gg;
    const int sid0 = 260 * gg - 4 * gg * gg + (ri & 7) * nseg;
    const int tj = r >> 7, cc = r & 127;
    const int nr = 2 * tj + 2;                  // strips covering col tile tj
    const int T = 2 * nseg + 2 * nr;

    if (chunk == 0 && r == 0) out[0] = 0.0f;

    float s = 0.0f;
    for (int m = chunk; m < T; m += NCHUNK) {
        size_t addr;
        if (m < 2 * nseg) {
            const int sg = m >> 1;              // segment within strip
            addr = (size_t)(sid0 + sg) * PSTRIDE + (m & 1) * 64 + rr;
        } else {
            const int m2 = m - 2 * nseg;
            const int rip = m2 >> 1;            // source strip
            const int dtj = tj - (rip >> 1);
            const int gp = rip >> 3;
            const int sidc = 260 * gp - 4 * gp * gp + (rip & 7) * (32 - gp)
                           + (dtj >> 2);
            addr = (size_t)sidc * PSTRIDE + 128 + (dtj & 3) * 256
                 + (m2 & 1) * 128 + cc;
        }
        s += part[addr];
    }
    S2[(size_t)chunk * NZ + r] = s;
}

// ---------------------------------------------------------------------------
// Kernel 4: loss + mean (two-stage path).
// ---------------------------------------------------------------------------
__global__ __launch_bounds__(256) void loss2_kernel(
    const float* __restrict__ S2, const float* __restrict__ pos,
    float* __restrict__ out)
{
    const int i = blockIdx.x * 256 + threadIdx.x;
    float den1 = 0.0f, den2 = 0.0f;
    #pragma unroll
    for (int c = 0; c < NCHUNK; ++c) {
        den1 += S2[(size_t)c * NZ + i];
        den2 += S2[(size_t)c * NZ + N_ROWS + i];
    }
    float v = 0.5f * (logf(den1) + logf(den2)) - TAU_INV * pos[i];

    __shared__ float red[4];
    #pragma unroll
    for (int m = 1; m < 64; m <<= 1) v += __shfl_xor(v, m, 64);
    if ((threadIdx.x & 63) == 0) red[threadIdx.x >> 6] = v;
    __syncthreads();
    if (threadIdx.x == 0)
        atomicAdd(out, (red[0] + red[1] + red[2] + red[3]) * (1.0f / N_ROWS));
}

// Fallback loss (atomic path, only if ws too small — never expected).
__global__ __launch_bounds__(256) void loss_kernel(
    const float* __restrict__ S, const float* __restrict__ pos,
    float* __restrict__ out)
{
    const int i = blockIdx.x * 256 + threadIdx.x;
    float v = 0.5f * (logf(S[i]) + logf(S[N_ROWS + i])) - TAU_INV * pos[i];

    __shared__ float red[4];
    #pragma unroll
    for (int m = 1; m < 64; m <<= 1) v += __shfl_xor(v, m, 64);
    if ((threadIdx.x & 63) == 0) red[threadIdx.x >> 6] = v;
    __syncthreads();
    if (threadIdx.x == 0)
        atomicAdd(out, (red[0] + red[1] + red[2] + red[3]) * (1.0f / N_ROWS));
}

// ---------------------------------------------------------------------------
extern "C" void kernel_launch(void* const* d_in, const int* in_sizes, int n_in,
                              void* d_out, int out_size, void* d_ws, size_t ws_size,
                              hipStream_t stream)
{
    const float* z1 = (const float*)d_in[0];
    const float* z2 = (const float*)d_in[1];
    float* out = (float*)d_out;

    char* ws = (char*)d_ws;
    unsigned char* Z8 = (unsigned char*)ws;              // 16384*256 = 4 MB
    float* pos  = (float*)(ws + 4194304);                // 32 KB
    float* S2   = (float*)(ws + 4227072);                // 16*16384*4 = 1 MB
    float* part = (float*)(ws + 5275648);                // 4224*1152*4 = 19.5 MB
    const size_t need = 5275648 + (size_t)NSEG * PSTRIDE * 4;

    normalize_kernel<<<N_ROWS / 4, 256, 0, stream>>>(z1, z2, Z8, pos);

    if (ws_size >= need) {
        gram_kernel<true><<<NSEG, 256, 0, stream>>>(Z8, part, nullptr);
        dim3 rg(NZ / 256, NCHUNK);
        reduce_kernel<<<rg, 256, 0, stream>>>(part, S2, out);   // zeroes out
        loss2_kernel<<<N_ROWS / 256, 256, 0, stream>>>(S2, pos, out);
    } else {
        hipMemsetAsync(S2, 0, NZ * sizeof(float), stream);
        hipMemsetAsync(out, 0, sizeof(float), stream);
        gram_kernel<false><<<NSEG, 256, 0, stream>>>(Z8, nullptr, S2);
        loss_kernel<<<N_ROWS / 256, 256, 0, stream>>>(S2, pos, out);
    }
}